// Round 1
// baseline (545.608 us; speedup 1.0000x reference)
//
#include <hip/hip_runtime.h>

// GeometricEmbedding, R2: split the fused kernel into two specialized kernels.
//
//  A) rbf_kernel  — 8 lanes per pair, zero shuffles / zero LDS. Each lane
//     redundantly recomputes d (the 8 replicated loads coalesce/merge in L1),
//     evaluates 4 exp2 and emits ONE nontemporal float4 store. Pure write
//     stream -> should run at write BW (~75 us for 410 MB).
//  B) chi_kernel  — the proven wave-level segmented reduction, with the whole
//     rbf/store phase removed (it was 71 ds_bpermute per wave in front of the
//     stores in the fused version). ~40 MB reads + 3 MB atomics.
//
// Rationale: fused kernel measured ~226 us vs ~72 us logical-traffic roofline;
// per-wave LDS-pipe occupancy (71 bpermutes) and L1-missing gathers sat in the
// store dependency chain, so no pipe saturated. Specialization decouples them.

#define NRBF 32
constexpr float R_CUT   = 5.0f;
constexpr float WIDTH   = R_CUT / NRBF;            // 0.15625
constexpr float INV_W   = 1.0f / WIDTH;            // 6.4
constexpr float CSPACE  = R_CUT / (NRBF - 1);      // linspace(0,5,32) spacing
constexpr float PI_F    = 3.14159265358979323846f;
constexpr float LOG2E   = 1.44269504088896340736f;
// exp(-0.5*((d-c)/W)^2) == exp2(A*(d-c)^2), A = -0.5*log2(e)/W^2
constexpr float EXP2_A  = -0.5f * LOG2E * INV_W * INV_W;
constexpr float C1  = 0.48860251190291992f;        // sqrt(3/(4pi))
constexpr float C2A = 1.09254843059207907f;        // 0.5*sqrt(15/pi)
constexpr float C2B = 0.31539156525252005f;        // 0.25*sqrt(5/pi)
constexpr float C2C = 0.54627421529603953f;        // 0.25*sqrt(15/pi)

typedef float f32x4 __attribute__((ext_vector_type(4)));

// ---------------------------------------------------------------------------
// Kernel A: rbf. 8 lanes per pair; lane sub stores elements [4*sub, 4*sub+4).
// Wave covers 8 consecutive pairs -> one fully-contiguous 1 KB store per wave.
// ---------------------------------------------------------------------------
__global__ __launch_bounds__(256) void rbf_kernel(
    const float* __restrict__ R,
    const float* __restrict__ pair_mask,
    const int*   __restrict__ idx_i,
    const int*   __restrict__ idx_j,
    float*       __restrict__ rbf_out,
    int n_pairs)
{
    const int t   = blockIdx.x * blockDim.x + threadIdx.x;
    const int p   = t >> 3;       // pair index
    const int sub = t & 7;        // which float4 of the 32-wide row
    if (p >= n_pairs) return;

    const int   i = idx_i[p];     // 8-way replicated loads: same line, L1-merged
    const int   j = idx_j[p];
    const float m = pair_mask[p];

    // r_ij = (R[j] - R[i]) * m ; d = |r_ij| * m  (sqrtf(0)==0 matches ref)
    const float rx = (R[3*j+0] - R[3*i+0]) * m;
    const float ry = (R[3*j+1] - R[3*i+1]) * m;
    const float rz = (R[3*j+2] - R[3*i+2]) * m;
    const float d  = sqrtf(rx*rx + ry*ry + rz*rz) * m;

    const float d0 = d - (float)(4 * sub) * CSPACE;
    const float a = d0;
    const float b = d0 - CSPACE;
    const float c = d0 - 2.0f * CSPACE;
    const float e = d0 - 3.0f * CSPACE;

    f32x4 v;
    v.x = __builtin_amdgcn_exp2f(EXP2_A * a * a) * m;
    v.y = __builtin_amdgcn_exp2f(EXP2_A * b * b) * m;
    v.z = __builtin_amdgcn_exp2f(EXP2_A * c * c) * m;
    v.w = __builtin_amdgcn_exp2f(EXP2_A * e * e) * m;

    // nontemporal: rbf_out is never re-read; keep the 1.2 MB R table in L2.
    __builtin_nontemporal_store(
        v, (f32x4*)(rbf_out + (size_t)p * NRBF + 4 * sub));
}

// ---------------------------------------------------------------------------
// Kernel B: chi. One thread per pair; wave-level segmented reduction over the
// sorted idx_i runs, head lanes emit 8 unsafeAtomicAdds. (Identical math to
// the verified fused kernel; rbf phase removed.)
// ---------------------------------------------------------------------------
__global__ __launch_bounds__(256) void chi_kernel(
    const float* __restrict__ R,
    const float* __restrict__ pair_mask,
    const float* __restrict__ point_mask,
    const int*   __restrict__ idx_i,
    const int*   __restrict__ idx_j,
    float*       __restrict__ chi_out,
    int n_pairs)
{
    const int p    = blockIdx.x * blockDim.x + threadIdx.x;
    const int lane = threadIdx.x & 63;

    int   seg = -1;          // idx_i value; -1 for inactive lanes
    float w[8];
    #pragma unroll
    for (int c = 0; c < 8; ++c) w[c] = 0.0f;

    if (p < n_pairs) {
        const int i = idx_i[p];
        const int j = idx_j[p];
        const float m = pair_mask[p];
        seg = i;

        const float rx = (R[3*j+0] - R[3*i+0]) * m;
        const float ry = (R[3*j+1] - R[3*i+1]) * m;
        const float rz = (R[3*j+2] - R[3*i+2]) * m;

        const float sq = rx*rx + ry*ry + rz*rz;
        const float d  = sqrtf(sq) * m;

        // cutoff envelope
        float phi = 0.5f * (__cosf(PI_F * d * (1.0f / R_CUT)) + 1.0f);
        phi *= (d < R_CUT) ? 1.0f : 0.0f;
        phi *= m;

        // unit vector (ref: 0 when d==0)
        const float inv_d = (d != 0.0f) ? (1.0f / d) : 0.0f;
        const float ux = rx * inv_d * m;
        const float uy = ry * inv_d * m;
        const float uz = rz * inv_d * m;

        float s[8];
        s[0] = C1  * uy;
        s[1] = C1  * uz;
        s[2] = C1  * ux;
        s[3] = C2A * ux * uy;
        s[4] = C2A * uy * uz;
        s[5] = C2B * (3.0f * uz * uz - 1.0f) * m;  // not zero-guarded in ref
        s[6] = C2A * ux * uz;
        s[7] = C2C * (ux * ux - uy * uy);

        const float scale = phi * point_mask[i];   // LAMBDA == 1
        #pragma unroll
        for (int c = 0; c < 8; ++c) w[c] = s[c] * scale;
    }

    // wave-level segmented reduction over sorted idx_i runs
    #pragma unroll
    for (int off = 1; off < 64; off <<= 1) {
        const int  oseg = __shfl_down(seg, off, 64);
        const bool ok   = (lane + off < 64) && (oseg == seg);
        #pragma unroll
        for (int c = 0; c < 8; ++c) {
            const float ow = __shfl_down(w[c], off, 64);
            if (ok) w[c] += ow;
        }
    }
    const int  pseg = __shfl_up(seg, 1, 64);
    const bool head = (lane == 0) || (pseg != seg);
    if (head && seg >= 0) {
        float* dst = chi_out + (size_t)seg * 8;
        #pragma unroll
        for (int c = 0; c < 8; ++c) unsafeAtomicAdd(dst + c, w[c]);
    }
}

extern "C" void kernel_launch(void* const* d_in, const int* in_sizes, int n_in,
                              void* d_out, int out_size, void* d_ws, size_t ws_size,
                              hipStream_t stream) {
    const float* R          = (const float*)d_in[0];
    const float* pair_mask  = (const float*)d_in[1];
    const float* point_mask = (const float*)d_in[2];
    const int*   idx_i      = (const int*)d_in[3];
    const int*   idx_j      = (const int*)d_in[4];
    // d_in[5] = z (unused by reference outputs)

    const int n_pairs = in_sizes[1];   // pair_mask length
    const int n       = in_sizes[2];   // point_mask length

    float* rbf_out = (float*)d_out;                       // [n_pairs, 32]
    float* chi_out = rbf_out + (size_t)n_pairs * NRBF;    // [n, 8]

    // harness poisons d_out with 0xAA before every timed launch
    hipMemsetAsync(chi_out, 0, (size_t)n * 8 * sizeof(float), stream);

    {   // A: 8 threads per pair
        const int threads = 256;
        const long long tot = (long long)n_pairs * 8;
        const int grid = (int)((tot + threads - 1) / threads);
        rbf_kernel<<<grid, threads, 0, stream>>>(
            R, pair_mask, idx_i, idx_j, rbf_out, n_pairs);
    }
    {   // B: 1 thread per pair
        const int threads = 256;
        const int grid = (n_pairs + threads - 1) / threads;
        chi_kernel<<<grid, threads, 0, stream>>>(
            R, pair_mask, point_mask, idx_i, idx_j, chi_out, n_pairs);
    }
}

// Round 3
// 488.001 us; speedup vs baseline: 1.1180x; 1.1180x over previous
//
#include <hip/hip_runtime.h>

// GeometricEmbedding, R3 (resubmit — R2 bench was an infra failure, no data):
// fused kernel (R0 structure) with the cross-lane work moved off the per-CU
// LDS pipe onto the VALU:
//
//  * segmented reduction: DPP-based inclusive segmented PREFIX scan
//    (row_shr:1/2/4/8 + row_bcast:15/31, all VALU) with segment conditions
//    derived from one __ballot(head). Tail lanes emit the atomics.
//    Replaces 54 ds_bpermute + 6 seg shuffles + 1 head shuffle.
//  * rbf broadcast: mask folded into d (d_bc = m!=0 ? d : 1e30 -> exp2 gives
//    exact 0 for masked pairs since masks are 0/1), so only d is shuffled:
//    16 bpermutes -> 8, and the per-element *m multiply disappears.
//
// LDS-pipe ops per wave: 71 -> 9. R0 fused measured ~226 us vs ~70 us
// traffic floor; model says ~46 us was LDS-pipe occupancy plus a ~900-cyc
// dependent-LDS scan chain per wave throttling latency hiding.

#define NRBF 32
constexpr float R_CUT   = 5.0f;
constexpr float WIDTH   = R_CUT / NRBF;            // 0.15625
constexpr float INV_W   = 1.0f / WIDTH;            // 6.4
constexpr float CSPACE  = R_CUT / (NRBF - 1);      // linspace(0,5,32) spacing
constexpr float PI_F    = 3.14159265358979323846f;
constexpr float LOG2E   = 1.44269504088896340736f;
// exp(-0.5*((d-c)/W)^2) == exp2(A*(d-c)^2), A = -0.5*log2(e)/W^2
constexpr float EXP2_A  = -0.5f * LOG2E * INV_W * INV_W;
constexpr float C1  = 0.48860251190291992f;        // sqrt(3/(4pi))
constexpr float C2A = 1.09254843059207907f;        // 0.5*sqrt(15/pi)
constexpr float C2B = 0.31539156525252005f;        // 0.25*sqrt(5/pi)
constexpr float C2C = 0.54627421529603953f;        // 0.25*sqrt(15/pi)

// DPP controls (gfx9/CDNA encoding)
#define DPP_ROW_SHR(n)  (0x110 + (n))
#define DPP_ROW_BCAST15 0x142
#define DPP_ROW_BCAST31 0x143

template <int CTRL>
__device__ __forceinline__ float fdpp0(float x) {
    // bound_ctrl=true: out-of-pattern lanes read 0
    return __int_as_float(__builtin_amdgcn_update_dpp(
        0, __float_as_int(x), CTRL, 0xF, 0xF, true));
}

__global__ __launch_bounds__(256) void geom_pairs_kernel(
    const float* __restrict__ R,
    const float* __restrict__ pair_mask,
    const float* __restrict__ point_mask,
    const int*   __restrict__ idx_i,
    const int*   __restrict__ idx_j,
    float* __restrict__ rbf_out,
    float* __restrict__ chi_out,
    int n_pairs)
{
    const int p    = blockIdx.x * blockDim.x + threadIdx.x;
    const int lane = threadIdx.x & 63;

    int   seg  = -1;           // idx_i value; -1 for inactive lanes
    float d_bc = 1e30f;        // broadcast value: d, or 1e30 if masked/inactive
    float w[8];
    #pragma unroll
    for (int c = 0; c < 8; ++c) w[c] = 0.0f;

    if (p < n_pairs) {
        const int i = idx_i[p];
        const int j = idx_j[p];
        const float m = pair_mask[p];
        seg = i;

        // r_ij = (R[j] - R[i]) * m   (R is 1.2 MB -> L2-resident gathers)
        const float rx = (R[3*j+0] - R[3*i+0]) * m;
        const float ry = (R[3*j+1] - R[3*i+1]) * m;
        const float rz = (R[3*j+2] - R[3*i+2]) * m;

        const float sq = rx*rx + ry*ry + rz*rz;
        const float d  = sqrtf(sq) * m;   // sqrtf(0)==0 matches ref zero-guard

        // masks are {0,1}: m==0 -> d_bc=1e30 -> exp2(A*(1e30-c)^2)=exp2(-inf)=+0,
        // bit-exact with ref's exp(..)*0. (Fractional masks would deviate.)
        d_bc = (m != 0.0f) ? d : 1e30f;

        // --- cutoff envelope ---
        float phi = 0.5f * (__cosf(PI_F * d * (1.0f/R_CUT)) + 1.0f);
        phi *= (d < R_CUT) ? 1.0f : 0.0f;
        phi *= m;

        // --- unit vector (ref: 0 when d==0) ---
        const float inv_d = (d != 0.0f) ? (1.0f / d) : 0.0f;
        const float ux = rx * inv_d * m;
        const float uy = ry * inv_d * m;
        const float uz = rz * inv_d * m;

        float s[8];
        s[0] = C1  * uy;
        s[1] = C1  * uz;
        s[2] = C1  * ux;
        s[3] = C2A * ux * uy;
        s[4] = C2A * uy * uz;
        s[5] = C2B * (3.0f * uz * uz - 1.0f) * m;  // not zero-guarded in ref
        s[6] = C2A * ux * uz;
        s[7] = C2C * (ux * ux - uy * uy);

        const float scale = phi * point_mask[i];   // LAMBDA == 1
        #pragma unroll
        for (int c = 0; c < 8; ++c) w[c] = s[c] * scale;
    }

    // --- rbf phase: 8 lanes per pair, fully coalesced float4 stores ---
    // Wave covers pairs [p-lane, p-lane+64) in 8 iterations of 8 pairs.
    {
        const long long wbase = (long long)(p - lane);  // wave-uniform
        const int sub = lane & 7;        // which 4-elem group this lane stores
        const int grp = lane >> 3;       // which pair within the iteration
        #pragma unroll
        for (int it = 0; it < 8; ++it) {
            const int srcl = it * 8 + grp;
            const float dd = __shfl(d_bc, srcl, 64);   // 1 bpermute / iter
            const long long pr = wbase + srcl;
            if (pr < (long long)n_pairs) {
                const float base = dd - (float)(4 * sub) * CSPACE;
                const float a0 = base;
                const float a1 = base - CSPACE;
                const float a2 = base - 2.0f * CSPACE;
                const float a3 = base - 3.0f * CSPACE;
                float4 v;
                v.x = __builtin_amdgcn_exp2f(EXP2_A * a0 * a0);
                v.y = __builtin_amdgcn_exp2f(EXP2_A * a1 * a1);
                v.z = __builtin_amdgcn_exp2f(EXP2_A * a2 * a2);
                v.w = __builtin_amdgcn_exp2f(EXP2_A * a3 * a3);
                *(float4*)(rbf_out + pr * NRBF + 4 * sub) = v;
            }
        }
    }

    // --- segmented reduction: DPP inclusive segmented prefix scan (VALU) ---
    // head/segment-start from one ballot; stage condition (lane-off) >= s.
    {
        const int prev_seg = __shfl_up(seg, 1, 64);              // 1 bpermute
        const bool head = (lane == 0) || (prev_seg != seg);
        const unsigned long long H = __ballot(head);
        const unsigned long long below = (2ull << lane) - 1ull;  // bits [0..lane]
        const int s = 63 - __clzll(H & below);                   // segment start

        // offsets 1,2,4,8: row_shr (zero-fills across row boundary; the
        // missing cross-row part is supplied exactly by bcast15/bcast31).
        {
            const bool ok = (lane - 1) >= s;
            #pragma unroll
            for (int c = 0; c < 8; ++c) { float t = fdpp0<DPP_ROW_SHR(1)>(w[c]); if (ok) w[c] += t; }
        }
        {
            const bool ok = (lane - 2) >= s;
            #pragma unroll
            for (int c = 0; c < 8; ++c) { float t = fdpp0<DPP_ROW_SHR(2)>(w[c]); if (ok) w[c] += t; }
        }
        {
            const bool ok = (lane - 4) >= s;
            #pragma unroll
            for (int c = 0; c < 8; ++c) { float t = fdpp0<DPP_ROW_SHR(4)>(w[c]); if (ok) w[c] += t; }
        }
        {
            const bool ok = (lane - 8) >= s;
            #pragma unroll
            for (int c = 0; c < 8; ++c) { float t = fdpp0<DPP_ROW_SHR(8)>(w[c]); if (ok) w[c] += t; }
        }
        {   // lane15 -> row1, lane47 -> row3 (odd rows only)
            const bool ok = ((lane >> 4) & 1) && (s < (lane & ~15));
            #pragma unroll
            for (int c = 0; c < 8; ++c) { float t = fdpp0<DPP_ROW_BCAST15>(w[c]); if (ok) w[c] += t; }
        }
        {   // lane31 -> lanes 32..63
            const bool ok = (lane >= 32) && (s < 32);
            #pragma unroll
            for (int c = 0; c < 8; ++c) { float t = fdpp0<DPP_ROW_BCAST31>(w[c]); if (ok) w[c] += t; }
        }

        // tail lanes hold full segment sums (prefix scan)
        const bool tail = (lane == 63) || (((H >> 1) >> lane) & 1ull);
        if (tail && seg >= 0) {
            float* dst = chi_out + (size_t)seg * 8;
            #pragma unroll
            for (int c = 0; c < 8; ++c) unsafeAtomicAdd(dst + c, w[c]);
        }
    }
}

extern "C" void kernel_launch(void* const* d_in, const int* in_sizes, int n_in,
                              void* d_out, int out_size, void* d_ws, size_t ws_size,
                              hipStream_t stream) {
    const float* R          = (const float*)d_in[0];
    const float* pair_mask  = (const float*)d_in[1];
    const float* point_mask = (const float*)d_in[2];
    const int*   idx_i      = (const int*)d_in[3];
    const int*   idx_j      = (const int*)d_in[4];
    // d_in[5] = z (unused by reference outputs)

    const int n_pairs = in_sizes[1];   // pair_mask length
    const int n       = in_sizes[2];   // point_mask length

    float* rbf_out = (float*)d_out;                       // [n_pairs, 32]
    float* chi_out = rbf_out + (size_t)n_pairs * NRBF;    // [n, 8]

    // harness poisons d_out with 0xAA before every timed launch
    hipMemsetAsync(chi_out, 0, (size_t)n * 8 * sizeof(float), stream);

    const int block = 256;
    const int grid  = (n_pairs + block - 1) / block;
    geom_pairs_kernel<<<grid, block, 0, stream>>>(
        R, pair_mask, point_mask, idx_i, idx_j, rbf_out, chi_out, n_pairs);
}

// Round 4
// 478.141 us; speedup vs baseline: 1.1411x; 1.0206x over previous
//
#include <hip/hip_runtime.h>

// GeometricEmbedding, R4: attack the gather/store interaction.
//   * R pre-packed to float4 in d_ws (pack kernel): 1 aligned dwordx4 gather
//     per endpoint instead of 3 scalar loads (L1 probe cycles /3).
//   * rbf stores nontemporal + idx/pair_mask loads nontemporal: keep the
//     1.2MB R table L2-resident instead of letting the 410MB write stream
//     thrash it (gather fills: HBM ~900cy -> L2 ~300cy).
//   * DPP segmented prefix scan + d-broadcast rbf phase retained from R3
//     (verified correct; LDS-pipe theory falsified but the code is fine).
//
// R3 post-mortem: removing 62/71 LDS ops changed nothing (490->488). VALU
// issue ~20us, BW floor ~72us, measured ~224us -> the gap must be the
// MSHR-limited random R-gathers at HBM-class latency under L2 write-thrash.

#define NRBF 32
constexpr float R_CUT   = 5.0f;
constexpr float WIDTH   = R_CUT / NRBF;            // 0.15625
constexpr float INV_W   = 1.0f / WIDTH;            // 6.4
constexpr float CSPACE  = R_CUT / (NRBF - 1);      // linspace(0,5,32) spacing
constexpr float PI_F    = 3.14159265358979323846f;
constexpr float LOG2E   = 1.44269504088896340736f;
// exp(-0.5*((d-c)/W)^2) == exp2(A*(d-c)^2), A = -0.5*log2(e)/W^2
constexpr float EXP2_A  = -0.5f * LOG2E * INV_W * INV_W;
constexpr float C1  = 0.48860251190291992f;        // sqrt(3/(4pi))
constexpr float C2A = 1.09254843059207907f;        // 0.5*sqrt(15/pi)
constexpr float C2B = 0.31539156525252005f;        // 0.25*sqrt(5/pi)
constexpr float C2C = 0.54627421529603953f;        // 0.25*sqrt(15/pi)

// DPP controls (gfx9/CDNA encoding)
#define DPP_ROW_SHR(n)  (0x110 + (n))
#define DPP_ROW_BCAST15 0x142
#define DPP_ROW_BCAST31 0x143

typedef float f32x4 __attribute__((ext_vector_type(4)));

template <int CTRL>
__device__ __forceinline__ float fdpp0(float x) {
    // bound_ctrl=true: out-of-pattern lanes read 0
    return __int_as_float(__builtin_amdgcn_update_dpp(
        0, __float_as_int(x), CTRL, 0xF, 0xF, true));
}

// ---------------------------------------------------------------------------
// pack kernel: R [n,3] -> R4 [n,4] (16B-aligned gathers for the main kernel)
// ---------------------------------------------------------------------------
__global__ __launch_bounds__(256) void pack_kernel(
    const float* __restrict__ R, float4* __restrict__ R4, int n)
{
    const int t = blockIdx.x * blockDim.x + threadIdx.x;
    if (t < n) R4[t] = make_float4(R[3*t+0], R[3*t+1], R[3*t+2], 0.0f);
}

// ---------------------------------------------------------------------------
// main fused kernel
// ---------------------------------------------------------------------------
template <bool PACKED>
__global__ __launch_bounds__(256) void geom_pairs_kernel(
    const float*  __restrict__ R,
    const float4* __restrict__ R4,
    const float*  __restrict__ pair_mask,
    const float*  __restrict__ point_mask,
    const int*    __restrict__ idx_i,
    const int*    __restrict__ idx_j,
    float* __restrict__ rbf_out,
    float* __restrict__ chi_out,
    int n_pairs)
{
    const int p    = blockIdx.x * blockDim.x + threadIdx.x;
    const int lane = threadIdx.x & 63;

    int   seg  = -1;           // idx_i value; -1 for inactive lanes
    float d_bc = 1e30f;        // broadcast value: d, or 1e30 if masked/inactive
    float w[8];
    #pragma unroll
    for (int c = 0; c < 8; ++c) w[c] = 0.0f;

    if (p < n_pairs) {
        // read-once streams: nontemporal to avoid polluting L2
        const int   i = __builtin_nontemporal_load(idx_i + p);
        const int   j = __builtin_nontemporal_load(idx_j + p);
        const float m = __builtin_nontemporal_load(pair_mask + p);
        seg = i;

        float rjx, rjy, rjz, rix, riy, riz;
        if (PACKED) {
            const float4 qj = R4[j];        // one aligned dwordx4 per endpoint
            const float4 qi = R4[i];
            rjx = qj.x; rjy = qj.y; rjz = qj.z;
            rix = qi.x; riy = qi.y; riz = qi.z;
        } else {
            rjx = R[3*j+0]; rjy = R[3*j+1]; rjz = R[3*j+2];
            rix = R[3*i+0]; riy = R[3*i+1]; riz = R[3*i+2];
        }

        // r_ij = (R[j] - R[i]) * m
        const float rx = (rjx - rix) * m;
        const float ry = (rjy - riy) * m;
        const float rz = (rjz - riz) * m;

        const float sq = rx*rx + ry*ry + rz*rz;
        const float d  = sqrtf(sq) * m;   // sqrtf(0)==0 matches ref zero-guard

        // masks are {0,1}: m==0 -> d_bc=1e30 -> exp2(-inf)=+0, bit-exact with
        // ref's exp(..)*0. (Fractional masks would deviate.)
        d_bc = (m != 0.0f) ? d : 1e30f;

        // --- cutoff envelope ---
        float phi = 0.5f * (__cosf(PI_F * d * (1.0f/R_CUT)) + 1.0f);
        phi *= (d < R_CUT) ? 1.0f : 0.0f;
        phi *= m;

        // --- unit vector (ref: 0 when d==0) ---
        const float inv_d = (d != 0.0f) ? (1.0f / d) : 0.0f;
        const float ux = rx * inv_d * m;
        const float uy = ry * inv_d * m;
        const float uz = rz * inv_d * m;

        float s[8];
        s[0] = C1  * uy;
        s[1] = C1  * uz;
        s[2] = C1  * ux;
        s[3] = C2A * ux * uy;
        s[4] = C2A * uy * uz;
        s[5] = C2B * (3.0f * uz * uz - 1.0f) * m;  // not zero-guarded in ref
        s[6] = C2A * ux * uz;
        s[7] = C2C * (ux * ux - uy * uy);

        const float scale = phi * point_mask[i];   // LAMBDA == 1
        #pragma unroll
        for (int c = 0; c < 8; ++c) w[c] = s[c] * scale;
    }

    // --- rbf phase: 8 lanes per pair, fully coalesced nontemporal stores ---
    // Wave covers pairs [p-lane, p-lane+64) in 8 iterations of 8 pairs.
    {
        const long long wbase = (long long)(p - lane);  // wave-uniform
        const int sub = lane & 7;        // which 4-elem group this lane stores
        const int grp = lane >> 3;       // which pair within the iteration
        #pragma unroll
        for (int it = 0; it < 8; ++it) {
            const int srcl = it * 8 + grp;
            const float dd = __shfl(d_bc, srcl, 64);   // 1 bpermute / iter
            const long long pr = wbase + srcl;
            if (pr < (long long)n_pairs) {
                const float base = dd - (float)(4 * sub) * CSPACE;
                const float a0 = base;
                const float a1 = base - CSPACE;
                const float a2 = base - 2.0f * CSPACE;
                const float a3 = base - 3.0f * CSPACE;
                f32x4 v;
                v.x = __builtin_amdgcn_exp2f(EXP2_A * a0 * a0);
                v.y = __builtin_amdgcn_exp2f(EXP2_A * a1 * a1);
                v.z = __builtin_amdgcn_exp2f(EXP2_A * a2 * a2);
                v.w = __builtin_amdgcn_exp2f(EXP2_A * a3 * a3);
                // nontemporal: rbf_out never re-read; keep R/idx in L2
                __builtin_nontemporal_store(
                    v, (f32x4*)(rbf_out + pr * NRBF + 4 * sub));
            }
        }
    }

    // --- segmented reduction: DPP inclusive segmented prefix scan (VALU) ---
    {
        const int prev_seg = __shfl_up(seg, 1, 64);              // 1 bpermute
        const bool head = (lane == 0) || (prev_seg != seg);
        const unsigned long long H = __ballot(head);
        const unsigned long long below = (2ull << lane) - 1ull;  // bits [0..lane]
        const int s = 63 - __clzll(H & below);                   // segment start

        {
            const bool ok = (lane - 1) >= s;
            #pragma unroll
            for (int c = 0; c < 8; ++c) { float t = fdpp0<DPP_ROW_SHR(1)>(w[c]); if (ok) w[c] += t; }
        }
        {
            const bool ok = (lane - 2) >= s;
            #pragma unroll
            for (int c = 0; c < 8; ++c) { float t = fdpp0<DPP_ROW_SHR(2)>(w[c]); if (ok) w[c] += t; }
        }
        {
            const bool ok = (lane - 4) >= s;
            #pragma unroll
            for (int c = 0; c < 8; ++c) { float t = fdpp0<DPP_ROW_SHR(4)>(w[c]); if (ok) w[c] += t; }
        }
        {
            const bool ok = (lane - 8) >= s;
            #pragma unroll
            for (int c = 0; c < 8; ++c) { float t = fdpp0<DPP_ROW_SHR(8)>(w[c]); if (ok) w[c] += t; }
        }
        {   // lane15 -> row1, lane47 -> row3 (odd 16-rows only)
            const bool ok = ((lane >> 4) & 1) && (s < (lane & ~15));
            #pragma unroll
            for (int c = 0; c < 8; ++c) { float t = fdpp0<DPP_ROW_BCAST15>(w[c]); if (ok) w[c] += t; }
        }
        {   // lane31 -> lanes 32..63
            const bool ok = (lane >= 32) && (s < 32);
            #pragma unroll
            for (int c = 0; c < 8; ++c) { float t = fdpp0<DPP_ROW_BCAST31>(w[c]); if (ok) w[c] += t; }
        }

        // tail lanes hold full segment sums (prefix scan)
        const bool tail = (lane == 63) || (((H >> 1) >> lane) & 1ull);
        if (tail && seg >= 0) {
            float* dst = chi_out + (size_t)seg * 8;
            #pragma unroll
            for (int c = 0; c < 8; ++c) unsafeAtomicAdd(dst + c, w[c]);
        }
    }
}

extern "C" void kernel_launch(void* const* d_in, const int* in_sizes, int n_in,
                              void* d_out, int out_size, void* d_ws, size_t ws_size,
                              hipStream_t stream) {
    const float* R          = (const float*)d_in[0];
    const float* pair_mask  = (const float*)d_in[1];
    const float* point_mask = (const float*)d_in[2];
    const int*   idx_i      = (const int*)d_in[3];
    const int*   idx_j      = (const int*)d_in[4];
    // d_in[5] = z (unused by reference outputs)

    const int n_pairs = in_sizes[1];   // pair_mask length
    const int n       = in_sizes[2];   // point_mask length

    float* rbf_out = (float*)d_out;                       // [n_pairs, 32]
    float* chi_out = rbf_out + (size_t)n_pairs * NRBF;    // [n, 8]

    // harness poisons d_out with 0xAA before every timed launch
    hipMemsetAsync(chi_out, 0, (size_t)n * 8 * sizeof(float), stream);

    const int block = 256;
    const int grid  = (n_pairs + block - 1) / block;

    const bool packed = (d_ws != nullptr) && (ws_size >= (size_t)n * 16);
    if (packed) {
        float4* R4 = (float4*)d_ws;
        pack_kernel<<<(n + block - 1) / block, block, 0, stream>>>(R, R4, n);
        geom_pairs_kernel<true><<<grid, block, 0, stream>>>(
            R, R4, pair_mask, point_mask, idx_i, idx_j, rbf_out, chi_out, n_pairs);
    } else {
        geom_pairs_kernel<false><<<grid, block, 0, stream>>>(
            R, nullptr, pair_mask, point_mask, idx_i, idx_j, rbf_out, chi_out, n_pairs);
    }
}